// Round 1
// baseline (413.843 us; speedup 1.0000x reference)
//
#include <hip/hip_runtime.h>
#include <math.h>

// Min-sum BP LDPC decoder, LDS-resident messages.
// One block = one batch element; msg[] (E=32768 floats = 128 KB) lives in LDS
// for all 10 iterations. Edges are contiguous per check (np.nonzero order),
// so check_adj[c,0] is the row start and check updates write contiguously.

#define BLOCK 1024
#define NV    8192          // N variables
#define MC    4096          // M checks
#define NE    32768         // E edges (N * DV, DV=4)
#define VPT   (NV / BLOCK)  // 8 vars per thread
#define CPT   (MC / BLOCK)  // 4 checks per thread
#define NITER 10
#define ALPHA 0.8f
#define CLAMP 20.0f

__global__ __launch_bounds__(BLOCK)
void bp_decode(const float* __restrict__ syndrome,    // (B, M)
               const float* __restrict__ llr_g,       // (B, N)
               const int*   __restrict__ var_adj,     // (N, 4)
               const int*   __restrict__ check_adj,   // (M, max_dc)
               const float* __restrict__ check_mask,  // (M, max_dc)
               const int*   __restrict__ var_idx,     // (E,)
               float* __restrict__ out,               // marginals | hard | converged
               int max_dc, int B)
{
    __shared__ float msg[NE];   // 128 KB: holds ctv, then vtc in-place
    __shared__ int   mism;

    const int b = blockIdx.x;
    const int t = threadIdx.x;

    // ctv0 = 0
    for (int e = t; e < NE; e += BLOCK) msg[e] = 0.0f;

    // ---- preload all per-thread read-only data into registers ----
    int   vadj[VPT][4];
    float llr[VPT];
#pragma unroll
    for (int k = 0; k < VPT; ++k) {
        const int v = t + k * BLOCK;
        const int4 a = ((const int4*)var_adj)[v];   // var degree is exactly 4
        vadj[k][0] = a.x; vadj[k][1] = a.y; vadj[k][2] = a.z; vadj[k][3] = a.w;
        llr[k] = llr_g[(size_t)b * NV + v];
    }
    int cstart[CPT], cdeg[CPT], sbit[CPT];
#pragma unroll
    for (int k = 0; k < CPT; ++k) {
        const int c = t + k * BLOCK;
        cstart[k] = check_adj[(size_t)c * max_dc];  // edges sorted by check -> row start
        int d = 0;
        for (int j = 0; j < max_dc; ++j)
            d += (check_mask[(size_t)c * max_dc + j] != 0.0f) ? 1 : 0;
        cdeg[k] = d;
        sbit[k] = (syndrome[(size_t)b * MC + c] > 0.5f) ? 1 : 0;
    }
    __syncthreads();

    for (int it = 0; it < NITER; ++it) {
        // ---- variable phase: msg(ctv) -> msg(vtc), in place ----
        // Each edge owned by exactly one var; threads own disjoint vars.
#pragma unroll
        for (int k = 0; k < VPT; ++k) {
            const float c0 = msg[vadj[k][0]];
            const float c1 = msg[vadj[k][1]];
            const float c2 = msg[vadj[k][2]];
            const float c3 = msg[vadj[k][3]];
            const float tot  = ((c0 + c1) + c2) + c3;   // reference sum order
            const float base = llr[k] + tot;
            msg[vadj[k][0]] = fminf(fmaxf(base - c0, -CLAMP), CLAMP);
            msg[vadj[k][1]] = fminf(fmaxf(base - c1, -CLAMP), CLAMP);
            msg[vadj[k][2]] = fminf(fmaxf(base - c2, -CLAMP), CLAMP);
            msg[vadj[k][3]] = fminf(fmaxf(base - c3, -CLAMP), CLAMP);
        }
        __syncthreads();

        // Reference pads the check gather with edge 0: absv_pad = |vtc[b,0]| + 1e6.
        // Matters only for dc<=1 checks; replicate exactly. Read before anyone
        // overwrites msg[0] in the check phase (hence the extra barrier).
        const float pad = fabsf(msg[0]) + 1.0e6f;
        __syncthreads();

        // ---- check phase: msg(vtc) -> msg(ctv_new), in place ----
#pragma unroll
        for (int k = 0; k < CPT; ++k) {
            const int st = cstart[k];
            const int d  = cdeg[k];
            float min1 = pad, min2 = pad;
            int par = 0;
            for (int j = 0; j < d; ++j) {
                const float x = msg[st + j];
                par ^= (x < 0.0f) ? 1 : 0;   // sign(0)=+1, sign(-0)=+1 like reference
                const float a = fabsf(x);
                if (a < min1) { min2 = min1; min1 = a; }
                else if (a < min2) { min2 = a; }
            }
            const int tb = sbit[k] ^ par;    // total sign bit incl. syndrome
            for (int j = 0; j < d; ++j) {
                const float x  = msg[st + j];
                const int  sb  = (x < 0.0f) ? 1 : 0;
                const float a  = fabsf(x);
                const float m  = (fabsf(a - min1) < 1e-9f) ? min2 : min1;  // ref tolerance
                const float val = ALPHA * m;
                msg[st + j] = (tb ^ sb) ? -val : val;
            }
        }
        __syncthreads();
    }

    // ---- finale: marginals, hard decisions, convergence ----
    float marg[VPT], hard[VPT];
#pragma unroll
    for (int k = 0; k < VPT; ++k) {
        const float c0 = msg[vadj[k][0]];
        const float c1 = msg[vadj[k][1]];
        const float c2 = msg[vadj[k][2]];
        const float c3 = msg[vadj[k][3]];
        const float tot = ((c0 + c1) + c2) + c3;
        const float tl  = llr[k] + tot;
        const float mg  = 1.0f / (1.0f + expf(tl));   // sigmoid(-tl)
        marg[k] = mg;
        hard[k] = (mg > 0.5f) ? 1.0f : 0.0f;
    }
    if (t == 0) mism = 0;
    __syncthreads();   // all msg reads done; safe to overwrite msg[0..NV)

    const size_t BN = (size_t)B * NV;
#pragma unroll
    for (int k = 0; k < VPT; ++k) {
        const int v = t + k * BLOCK;
        msg[v] = hard[k];                              // hard bits for parity check
        out[(size_t)b * NV + v]      = marg[k];        // output 0: marginals
        out[BN + (size_t)b * NV + v] = hard[k];        // output 1: hard_decision
    }
    __syncthreads();

    // syn_hat[c] = parity of hard bits of c's vars; converged iff == syndrome
#pragma unroll
    for (int k = 0; k < CPT; ++k) {
        const int st = cstart[k];
        const int d  = cdeg[k];
        int par = 0;
        for (int j = 0; j < d; ++j) {
            const int v = var_idx[st + j];
            par ^= (msg[v] != 0.0f) ? 1 : 0;
        }
        if (par != sbit[k]) mism = 1;   // benign race: all writers store 1
    }
    __syncthreads();
    if (t == 0) out[2 * BN + b] = mism ? 0.0f : 1.0f;  // output 2: converged
}

extern "C" void kernel_launch(void* const* d_in, const int* in_sizes, int n_in,
                              void* d_out, int out_size, void* d_ws, size_t ws_size,
                              hipStream_t stream) {
    const float* syndrome   = (const float*)d_in[0];
    const float* llr        = (const float*)d_in[1];
    const int*   var_adj    = (const int*)d_in[2];
    // d_in[3] var_adj_mask: all ones (DV=4 exact) — unused
    const int*   check_adj  = (const int*)d_in[4];
    const float* check_mask = (const float*)d_in[5];
    const int*   var_idx    = (const int*)d_in[6];
    // d_in[7] pcm_dense — unused (parity computed via edges)
    float* out = (float*)d_out;

    const int B      = in_sizes[0] / MC;      // 256
    const int max_dc = in_sizes[4] / MC;

    bp_decode<<<B, BLOCK, 0, stream>>>(syndrome, llr, var_adj, check_adj,
                                       check_mask, var_idx, out, max_dc, B);
}

// Round 2
// 395.495 us; speedup vs baseline: 1.0464x; 1.0464x over previous
//
#include <hip/hip_runtime.h>
#include <math.h>

// Min-sum BP LDPC decoder, LDS-resident messages, degree-sorted checks.
// One block = one batch element; msg[] (E=32768 floats = 128 KB) lives in LDS
// for all 10 iterations. Edges are contiguous per check (np.nonzero order).
//
// R1 changes vs R0:
//  - setup kernel counting-sorts checks by degree into d_ws -> wave-uniform
//    check loops (wave-max d ~15 -> ~8)
//  - check phase is single-pass: edge values cached in registers via a
//    degree-class ladder (d<=8 / d<=16 / generic fallback), 3 LDS ops/edge -> 2
//  - pad value published via shared slot during var phase: 3 -> 2 barriers/iter
//  - final parity via hard-bit scatter to edges (no var_idx gather)

#define BLOCK 1024
#define NV    8192          // N variables
#define MC    4096          // M checks
#define NE    32768         // E edges (N * DV, DV=4)
#define VPT   (NV / BLOCK)  // 8 vars per thread
#define CPT   (MC / BLOCK)  // 4 checks per thread
#define NITER 10
#define ALPHA 0.8f
#define CLAMP 20.0f

// ---------------- setup: counting-sort checks by degree ----------------
// ws[0..MC)    : (cstart & 0xFFFF) | (deg << 16), degree-sorted
// ws[MC..2MC)  : original check index (for syndrome lookup), same order
__global__ __launch_bounds__(BLOCK)
void setup_sort(const float* __restrict__ check_mask,
                const int*   __restrict__ check_adj,
                int max_dc, int* __restrict__ ws)
{
    __shared__ int hist[64];
    __shared__ int base[64];
    const int t = threadIdx.x;
    if (t < 64) hist[t] = 0;
    __syncthreads();
    int deg[CPT], cst[CPT];
#pragma unroll
    for (int k = 0; k < CPT; ++k) {
        const int c = t + k * BLOCK;
        int d = 0;
        for (int j = 0; j < max_dc; ++j)
            d += (check_mask[(size_t)c * max_dc + j] != 0.0f) ? 1 : 0;
        deg[k] = d;
        cst[k] = check_adj[(size_t)c * max_dc];  // row start (edges sorted by check)
        atomicAdd(&hist[d & 63], 1);
    }
    __syncthreads();
    if (t == 0) {
        int s = 0;
        for (int i = 0; i < 64; ++i) { base[i] = s; s += hist[i]; }
    }
    __syncthreads();
#pragma unroll
    for (int k = 0; k < CPT; ++k) {
        const int c   = t + k * BLOCK;
        const int pos = atomicAdd(&base[deg[k] & 63], 1);
        ws[pos]      = (cst[k] & 0xFFFF) | (deg[k] << 16);
        ws[MC + pos] = c;
    }
}

// Single-pass check update with register-cached edge values.
// DMAX is a compile-time cap; loops fully unrolled so x[] stays in VGPRs.
template<int DMAX>
__device__ __forceinline__ void do_check(float* __restrict__ msg,
                                         int st, int d, int tbsyn, float pad)
{
    float x[DMAX];
    float min1 = pad, min2 = pad;
    int par = 0;
#pragma unroll
    for (int j = 0; j < DMAX; ++j) {
        if (j >= d) break;
        x[j] = msg[st + j];
    }
#pragma unroll
    for (int j = 0; j < DMAX; ++j) {
        if (j >= d) break;
        par ^= (x[j] < 0.0f) ? 1 : 0;           // sign(0)=+1 like reference
        const float a = fabsf(x[j]);
        if (a < min1) { min2 = min1; min1 = a; }
        else if (a < min2) { min2 = a; }
    }
    const int tb = tbsyn ^ par;
#pragma unroll
    for (int j = 0; j < DMAX; ++j) {
        if (j >= d) break;
        const float a   = fabsf(x[j]);
        const float m   = (fabsf(a - min1) < 1e-9f) ? min2 : min1;  // ref tolerance
        const float val = ALPHA * m;
        msg[st + j] = ((tb ^ ((x[j] < 0.0f) ? 1 : 0)) ? -val : val);
    }
}

// Generic fallback for d > 16 (rare; re-reads LDS instead of caching).
__device__ __forceinline__ void do_check_big(float* __restrict__ msg,
                                             int st, int d, int tbsyn, float pad)
{
    float min1 = pad, min2 = pad;
    int par = 0;
    for (int j = 0; j < d; ++j) {
        const float xx = msg[st + j];
        par ^= (xx < 0.0f) ? 1 : 0;
        const float a = fabsf(xx);
        if (a < min1) { min2 = min1; min1 = a; }
        else if (a < min2) { min2 = a; }
    }
    const int tb = tbsyn ^ par;
    for (int j = 0; j < d; ++j) {
        const float xx  = msg[st + j];
        const float a   = fabsf(xx);
        const float m   = (fabsf(a - min1) < 1e-9f) ? min2 : min1;
        const float val = ALPHA * m;
        msg[st + j] = ((tb ^ ((xx < 0.0f) ? 1 : 0)) ? -val : val);
    }
}

__global__ __launch_bounds__(BLOCK)
void bp_decode(const float* __restrict__ syndrome,    // (B, M)
               const float* __restrict__ llr_g,       // (B, N)
               const int*   __restrict__ var_adj,     // (N, 4)
               const int*   __restrict__ ws,          // sorted check info
               float* __restrict__ out,               // marginals | hard | converged
               int B)
{
    __shared__ float msg[NE];   // 128 KB: ctv, then vtc in-place
    __shared__ float sh_e0;     // |vtc[edge 0]| snapshot for reference's pad
    __shared__ int   mism;

    const int b = blockIdx.x;
    const int t = threadIdx.x;

    for (int e = t; e < NE; e += BLOCK) msg[e] = 0.0f;   // ctv0 = 0

    // ---- preload per-thread read-only data into registers ----
    int   vadj[VPT][4];
    float llr[VPT];
    bool  e0own = false;
#pragma unroll
    for (int k = 0; k < VPT; ++k) {
        const int v = t + k * BLOCK;
        const int4 a = ((const int4*)var_adj)[v];   // var degree is exactly 4
        vadj[k][0] = a.x; vadj[k][1] = a.y; vadj[k][2] = a.z; vadj[k][3] = a.w;
        e0own |= (a.x == 0) | (a.y == 0) | (a.z == 0) | (a.w == 0);
        llr[k] = llr_g[(size_t)b * NV + v];
    }
    int cst[CPT], dsb[CPT];   // dsb = (deg<<1) | syndrome_bit
#pragma unroll
    for (int k = 0; k < CPT; ++k) {
        const int i = t + k * BLOCK;
        const int w = ws[i];
        const int c = ws[MC + i];
        cst[k] = w & 0xFFFF;
        const int d  = w >> 16;
        const int sb = (syndrome[(size_t)b * MC + c] > 0.5f) ? 1 : 0;
        dsb[k] = (d << 1) | sb;
    }
    __syncthreads();

    for (int it = 0; it < NITER; ++it) {
        // ---- variable phase: msg(ctv) -> msg(vtc), in place ----
#pragma unroll
        for (int k = 0; k < VPT; ++k) {
            const float c0 = msg[vadj[k][0]];
            const float c1 = msg[vadj[k][1]];
            const float c2 = msg[vadj[k][2]];
            const float c3 = msg[vadj[k][3]];
            const float tot  = ((c0 + c1) + c2) + c3;   // reference sum order
            const float base = llr[k] + tot;
            msg[vadj[k][0]] = fminf(fmaxf(base - c0, -CLAMP), CLAMP);
            msg[vadj[k][1]] = fminf(fmaxf(base - c1, -CLAMP), CLAMP);
            msg[vadj[k][2]] = fminf(fmaxf(base - c2, -CLAMP), CLAMP);
            msg[vadj[k][3]] = fminf(fmaxf(base - c3, -CLAMP), CLAMP);
        }
        // Reference pads short checks with edge 0's value: |vtc[0]| + 1e6.
        // Edge 0's owner just wrote msg[0]; publish before the barrier.
        if (e0own) sh_e0 = fabsf(msg[0]) + 1.0e6f;
        __syncthreads();
        const float pad = sh_e0;

        // ---- check phase: msg(vtc) -> msg(ctv_new), in place ----
#pragma unroll
        for (int k = 0; k < CPT; ++k) {
            const int d  = dsb[k] >> 1;
            const int sb = dsb[k] & 1;
            const int st = cst[k];
            if (d <= 8)       do_check<8>(msg, st, d, sb, pad);
            else if (d <= 16) do_check<16>(msg, st, d, sb, pad);
            else              do_check_big(msg, st, d, sb, pad);
        }
        __syncthreads();
    }

    // ---- finale: marginals, hard decisions, convergence ----
    float marg[VPT], hard[VPT];
#pragma unroll
    for (int k = 0; k < VPT; ++k) {
        const float c0 = msg[vadj[k][0]];
        const float c1 = msg[vadj[k][1]];
        const float c2 = msg[vadj[k][2]];
        const float c3 = msg[vadj[k][3]];
        const float tot = ((c0 + c1) + c2) + c3;
        const float tl  = llr[k] + tot;
        const float mg  = 1.0f / (1.0f + expf(tl));   // sigmoid(-tl)
        marg[k] = mg;
        hard[k] = (mg > 0.5f) ? 1.0f : 0.0f;
    }
    if (t == 0) mism = 0;
    __syncthreads();   // all ctv reads done; safe to overwrite msg

    const size_t BN = (size_t)B * NV;
#pragma unroll
    for (int k = 0; k < VPT; ++k) {
        const int v = t + k * BLOCK;
        out[(size_t)b * NV + v]      = marg[k];        // output 0: marginals
        out[BN + (size_t)b * NV + v] = hard[k];        // output 1: hard_decision
        const float h = hard[k];                       // scatter hard bit to edges
        msg[vadj[k][0]] = h;
        msg[vadj[k][1]] = h;
        msg[vadj[k][2]] = h;
        msg[vadj[k][3]] = h;
    }
    __syncthreads();

    // syn_hat[c] = parity over the check's edges' hard bits; converged iff == syndrome
#pragma unroll
    for (int k = 0; k < CPT; ++k) {
        const int d  = dsb[k] >> 1;
        const int sb = dsb[k] & 1;
        const int st = cst[k];
        int par = 0;
        for (int j = 0; j < d; ++j)
            par ^= (msg[st + j] != 0.0f) ? 1 : 0;
        if (par != sb) mism = 1;   // benign race: all writers store 1
    }
    __syncthreads();
    if (t == 0) out[2 * BN + b] = mism ? 0.0f : 1.0f;  // output 2: converged
}

extern "C" void kernel_launch(void* const* d_in, const int* in_sizes, int n_in,
                              void* d_out, int out_size, void* d_ws, size_t ws_size,
                              hipStream_t stream) {
    const float* syndrome   = (const float*)d_in[0];
    const float* llr        = (const float*)d_in[1];
    const int*   var_adj    = (const int*)d_in[2];
    // d_in[3] var_adj_mask: all ones (DV=4 exact) — unused
    const int*   check_adj  = (const int*)d_in[4];
    const float* check_mask = (const float*)d_in[5];
    // d_in[6] var_idx — unused (parity via hard-bit scatter)
    // d_in[7] pcm_dense — unused
    float* out = (float*)d_out;
    int*   ws  = (int*)d_ws;    // needs 2*MC ints = 32 KB

    const int B      = in_sizes[0] / MC;      // 256
    const int max_dc = in_sizes[4] / MC;

    setup_sort<<<1, BLOCK, 0, stream>>>(check_mask, check_adj, max_dc, ws);
    bp_decode<<<B, BLOCK, 0, stream>>>(syndrome, llr, var_adj, ws, out, B);
}